// Round 1
// baseline (185.976 us; speedup 1.0000x reference)
//
#include <hip/hip_runtime.h>
#include <hip/hip_bf16.h>

// Problem constants (fixed by reference setup_inputs)
#define M_DIM 32
#define I_DIM 7168
#define O_DIM 18432
#define SW    56      // I_DIM / 128 (scale row stride)
#define BN    64      // N-cols per block (2 waves x 32)
#define NT    288     // O_DIM / BN
#define KC    8       // split-K factor
#define KCHUNK 896    // I_DIM / KC

typedef __attribute__((ext_vector_type(8)))  __bf16        bf16x8;
typedef __attribute__((ext_vector_type(8)))  unsigned short u16x8;
typedef __attribute__((ext_vector_type(16))) float          f32x16;

// fp32 -> bf16 round-to-nearest-even
__device__ __forceinline__ unsigned short f2bf(float f) {
  unsigned u = __float_as_uint(f);
  u += 0x7FFF + ((u >> 16) & 1);
  return (unsigned short)(u >> 16);
}

__global__ __launch_bounds__(128, 4) void fp8lin_gemm(
    const float* __restrict__ x,      // [32, 7168]
    const float* __restrict__ w,      // [18432, 7168]
    const float* __restrict__ s,      // [144, 56]
    float* __restrict__ out) {        // [32, 18432], pre-zeroed
  const int bid   = blockIdx.x;
  const int ntile = bid % NT;        // consecutive blocks -> consecutive O tiles (same kc)
  const int kc    = bid / NT;
  const int wid   = threadIdx.x >> 6;
  const int lane  = threadIdx.x & 63;
  const int r     = lane & 31;       // A row (m) and B col offset
  const int g     = lane >> 5;       // k-group: k = g*8 + j

  const int o0 = ntile * BN + wid * 32;
  const int sbase = (o0 >> 7) * SW;  // all 32 cols share one 128-block of scales

  const float* __restrict__ xrow = x + (size_t)r * I_DIM;
  const float* __restrict__ wrow = w + (size_t)(o0 + r) * I_DIM;

  f32x16 acc;
#pragma unroll
  for (int i = 0; i < 16; ++i) acc[i] = 0.0f;

  const int kbeg = kc * KCHUNK;
  const int kend = kbeg + KCHUNK;

#pragma unroll 4
  for (int k0 = kbeg; k0 < kend; k0 += 16) {
    const int kb = k0 + g * 8;
    const float4 a0 = *reinterpret_cast<const float4*>(xrow + kb);
    const float4 a1 = *reinterpret_cast<const float4*>(xrow + kb + 4);
    const float4 b0 = *reinterpret_cast<const float4*>(wrow + kb);
    const float4 b1 = *reinterpret_cast<const float4*>(wrow + kb + 4);
    const float  sc = s[sbase + (k0 >> 7)];   // wave-uniform -> s_load

    u16x8 au, bu;
    au[0] = f2bf(a0.x); au[1] = f2bf(a0.y); au[2] = f2bf(a0.z); au[3] = f2bf(a0.w);
    au[4] = f2bf(a1.x); au[5] = f2bf(a1.y); au[6] = f2bf(a1.z); au[7] = f2bf(a1.w);
    bu[0] = f2bf(b0.x * sc); bu[1] = f2bf(b0.y * sc);
    bu[2] = f2bf(b0.z * sc); bu[3] = f2bf(b0.w * sc);
    bu[4] = f2bf(b1.x * sc); bu[5] = f2bf(b1.y * sc);
    bu[6] = f2bf(b1.z * sc); bu[7] = f2bf(b1.w * sc);

    acc = __builtin_amdgcn_mfma_f32_32x32x16_bf16(
        __builtin_bit_cast(bf16x8, au),
        __builtin_bit_cast(bf16x8, bu), acc, 0, 0, 0);
  }

  // C/D layout (32x32, verified m74/m101): col = lane&31, row = (reg&3) + 8*(reg>>2) + 4*(lane>>5)
  float* __restrict__ op = out + (o0 + r);
#pragma unroll
  for (int reg = 0; reg < 16; ++reg) {
    const int row = (reg & 3) + 8 * (reg >> 2) + 4 * g;
    __hip_atomic_fetch_add(op + (size_t)row * O_DIM, acc[reg],
                           __ATOMIC_RELAXED, __HIP_MEMORY_SCOPE_AGENT);
  }
}

extern "C" void kernel_launch(void* const* d_in, const int* in_sizes, int n_in,
                              void* d_out, int out_size, void* d_ws, size_t ws_size,
                              hipStream_t stream) {
  const float* x = (const float*)d_in[0];
  const float* w = (const float*)d_in[1];
  const float* s = (const float*)d_in[2];
  float* out = (float*)d_out;

  // Split-K accumulates with atomics; output must start at zero every call.
  hipMemsetAsync(out, 0, (size_t)out_size * sizeof(float), stream);

  dim3 grid(NT * KC);   // 2304 blocks = 9 per CU exactly
  dim3 block(128);      // 2 waves
  fp8lin_gemm<<<grid, block, 0, stream>>>(x, w, s, out);
}